// Round 8
// baseline (230.144 us; speedup 1.0000x reference)
//
#include <hip/hip_runtime.h>
#include <hip/hip_bf16.h>

typedef __attribute__((ext_vector_type(8))) short s16x8;
typedef __attribute__((ext_vector_type(4))) short s16x4;
typedef __attribute__((ext_vector_type(2))) short s16x2;
typedef __attribute__((ext_vector_type(4))) float f32x4;

#define BB 16
#define LL 2048
#define HH 768
#define DD 768
#define MM 8

// d_out layout (float elements)
#define O_LOGITS 0
#define O_BID    128
#define O_LID    256
#define O_AGGL   384
#define O_SCALE  98688
#define O_AGGT   98689

// ws layout (bytes)
#define WTT_OFF  0u            // 768*768 bf16 = 1179648
#define PT_OFF   1179648u      // 32768*768 bf16 = 50331648
#define SC_OFF   51511296u     // 16*8*2048 fp32 = 1048576
#define PART_OFF 52559872u     // 8*128*768 fp32 = 3145728
#define WLT_OFF  55705600u     // 768*768 bf16 = 1179648
#define HBAR_OFF 56885248u     // 128*768 fp32 = 393216

__device__ __forceinline__ short f2bf(float x) {
  union { float f; unsigned u; } v; v.f = x;
  unsigned r = v.u + 0x7FFFu + ((v.u >> 16) & 1u);
  return (short)(r >> 16);
}
__device__ __forceinline__ float bf2f(short x) {
  union { unsigned u; float f; } v; v.u = ((unsigned)(unsigned short)x) << 16;
  return v.f;
}

// async global->LDS, 16B per lane; LDS dest is wave-uniform base (HW adds lane*16)
#define GLOAD_LDS16(gp, lp) __builtin_amdgcn_global_load_lds( \
    (const __attribute__((address_space(1))) unsigned int*)(gp), \
    (__attribute__((address_space(3))) unsigned int*)(lp), 16, 0, 0)

// ---------------------------------------------------------------- W -> W^T bf16 (Wt and Wl)
__global__ void k_wt_transpose(const float* __restrict__ Wt, const float* __restrict__ Wl,
                               short* __restrict__ Wtt, short* __restrict__ Wlt) {
  __shared__ float tile[64][65];
  const float* src = blockIdx.z ? Wl : Wt;
  short* dst = blockIdx.z ? Wlt : Wtt;
  int kb = blockIdx.x * 64;
  int nb = blockIdx.y * 64;
  int t = threadIdx.x;
  int c = t & 63;
  int r0 = (t >> 6) * 16;
#pragma unroll
  for (int i = 0; i < 16; ++i)
    tile[r0 + i][c] = src[(size_t)(kb + r0 + i) * DD + nb + c];
  __syncthreads();
#pragma unroll
  for (int i = 0; i < 16; ++i)
    dst[(size_t)(nb + r0 + i) * HH + kb + c] = f2bf(tile[c][r0 + i]);
}

// ---------------------------------------------------------------- hbar = segment-mean of hs
__global__ void k_hbar(const float* __restrict__ hs, const int* __restrict__ lmask,
                       float* __restrict__ hbar) {
  int b = blockIdx.x >> 3, m = blockIdx.x & 7;
  int t = threadIdx.x;
  int lane = t & 63, w = t >> 6;
  __shared__ int list[LL];
  __shared__ int nlist_s;
  if (w == 0) {  // deterministic compaction of matching token indices
    int base = 0;
    for (int win = 0; win < LL / 64; ++win) {
      int l = win * 64 + lane;
      bool match = (lmask[b * LL + l] == m + 1);
      unsigned long long mk = __ballot(match);
      if (match) {
        int pos = base + (int)__popcll(mk & ((1ull << lane) - 1ull));
        list[pos] = l;
      }
      base += (int)__popcll(mk);
    }
    if (lane == 0) nlist_s = base;
  }
  __syncthreads();
  int n = nlist_s;
  float inv = 1.0f / (float)(n > 1 ? n : 1);
  float a0 = 0.f, a1 = 0.f, a2 = 0.f;
  for (int i = 0; i < n; ++i) {
    const float* r = hs + (size_t)(b * LL + list[i]) * HH;
    a0 += r[t]; a1 += r[t + 256]; a2 += r[t + 512];
  }
  float* dst = hbar + (size_t)(b * MM + m) * HH;
  dst[t] = a0 * inv; dst[t + 256] = a1 * inv; dst[t + 512] = a2 * inv;
}

// ---------------------------------------------------------------- shared GEMM body
// BM=128 x BN=256, 512 threads (8 waves, 2x4). A fp32 reg-staged -> cvt_pk ->
// bf16 LDS (single buffer); B bf16 double-buffered via global_load_lds.
// Full-drain __syncthreads structure (race-proven in round 6); loads for kt+1
// are issued before compute(kt) so the first barrier drain lands one
// compute-phase after issue. 16B-chunk XOR swizzle phys = c ^ (row&7) on both
// tiles (zero bank conflicts, measured round 6).
#define Bb_M 128
#define Bb_N 256
#define Bb_K 64
#define NTK 12

struct GemmAcc { f32x4 acc[4][4]; };

__device__ __forceinline__ void gemm_body(
    short* AsB, short* BsB,
    const float* A, const short* Bt, int m0, int n0, int lda_k,
    GemmAcc& g, int t) {
  int lane = t & 63;
  int w = t >> 6;           // 0..7
  int wm = w >> 2;          // 0..1
  int wn = w & 3;           // 0..3

  float4 areg[4];

  auto issueA = [&](int kt) {
    const float* Ag = A + (size_t)m0 * lda_k + kt * Bb_K;
#pragma unroll
    for (int i = 0; i < 4; ++i) {
      int slot = i * 512 + t;                  // 2048 16B fp32 chunks
      int row = slot >> 4, c = slot & 15;
      areg[i] = *(const float4*)(Ag + (size_t)row * lda_k + c * 4);
    }
  };
  auto issueB = [&](int kt, int buf) {
    const short* Bg = Bt + (size_t)n0 * lda_k + kt * Bb_K;
#pragma unroll
    for (int i = 0; i < 4; ++i) {
      int slot = i * 512 + t;                  // 2048 16B bf16 chunks (256 rows x 8)
      int row = slot >> 3, c = slot & 7;
      int cs = c ^ (row & 7);                  // inverse-swizzled global source
      GLOAD_LDS16(Bg + (size_t)row * lda_k + cs * 8,
                  (char*)BsB + (size_t)buf * 32768 + (size_t)(i * 512 + w * 64) * 16);
    }
  };
  auto writeA = [&]() {   // cvt_pk + swizzled ds_write
#pragma unroll
    for (int i = 0; i < 4; ++i) {
      int slot = i * 512 + t;
      int row = slot >> 4, c = slot & 15;      // c = 8B-unit index of bf16 row
      unsigned d0, d1;
      asm("v_cvt_pk_bf16_f32 %0, %1, %2" : "=v"(d0) : "v"(areg[i].x), "v"(areg[i].y));
      asm("v_cvt_pk_bf16_f32 %0, %1, %2" : "=v"(d1) : "v"(areg[i].z), "v"(areg[i].w));
      int phys = (c >> 1) ^ (row & 7);
      uint2 val = {d0, d1};
      *(uint2*)((char*)AsB + (size_t)row * 128 + phys * 16 + (c & 1) * 8) = val;
    }
  };
  auto compute = [&](int buf) {
#pragma unroll
    for (int kk = 0; kk < 2; ++kk) {
      s16x8 a[4], bb[4];
#pragma unroll
      for (int i = 0; i < 4; ++i) {
        int row = wm * 64 + i * 16 + (lane & 15);
        int p = (kk * 4 + (lane >> 4)) ^ (row & 7);
        a[i] = *(const s16x8*)((const char*)AsB + (size_t)row * 128 + p * 16);
      }
#pragma unroll
      for (int i = 0; i < 4; ++i) {
        int row = wn * 64 + i * 16 + (lane & 15);
        int p = (kk * 4 + (lane >> 4)) ^ (row & 7);
        bb[i] = *(const s16x8*)((const char*)BsB + (size_t)buf * 32768 + (size_t)row * 128 + p * 16);
      }
#pragma unroll
      for (int mi = 0; mi < 4; ++mi)
#pragma unroll
        for (int ni = 0; ni < 4; ++ni)
          g.acc[mi][ni] = __builtin_amdgcn_mfma_f32_16x16x32_bf16(a[mi], bb[ni], g.acc[mi][ni], 0, 0, 0);
    }
  };

  // prologue
  issueA(0); issueB(0, 0);
  writeA();                 // compiler auto-waits the areg loads
  __syncthreads();          // drains B(0) DMA + commits As(0)
  for (int kt = 0; kt < NTK; ++kt) {
    if (kt + 1 < NTK) { issueA(kt + 1); issueB(kt + 1, (kt + 1) & 1); }
    compute(kt & 1);        // kt+1 loads in flight during compute
    __syncthreads();        // drain (one compute-phase after issue); As free
    if (kt + 1 < NTK) {
      writeA();             // As(kt+1)
      __syncthreads();      // As(kt+1) + Bs[nxt] visible
    }
  }
}

// ---------------------------------------------------------------- proj_text GEMM (bf16 out)
__global__ __launch_bounds__(512, 2)
void k_gemm_pt(const float* __restrict__ A, const short* __restrict__ Bt,
               const float* __restrict__ bias, short* __restrict__ C) {
  __shared__ short As[Bb_M][Bb_K];        // 16 KB
  __shared__ short Bs[2][Bb_N][Bb_K];     // 64 KB
  int t = threadIdx.x;
  int lane = t & 63;
  int w = t >> 6;
  int wm = w >> 2, wn = w & 3;
  // XCD-affinity remap: 3 N-tiles of one M-panel land on the same XCD
  int id = blockIdx.x;           // 768
  int xcd = id & 7, q = id >> 3; // q 0..95
  int m0 = ((q / 3) * 8 + xcd) * Bb_M;
  int n0 = (q % 3) * Bb_N;

  GemmAcc g = {};
  gemm_body(&As[0][0], &Bs[0][0][0], A, Bt, m0, n0, HH, g, t);

#pragma unroll
  for (int mi = 0; mi < 4; ++mi) {
    int row = m0 + wm * 64 + mi * 16 + ((lane >> 4) * 4);
#pragma unroll
    for (int ni = 0; ni < 4; ++ni) {
      int col = n0 + wn * 64 + ni * 16 + (lane & 15);
      float bv = bias[col];
#pragma unroll
      for (int j = 0; j < 4; ++j)
        C[(size_t)(row + j) * DD + col] = f2bf(g.acc[mi][ni][j] + bv);
    }
  }
}

// ---------------------------------------------------------------- agg = hbar @ Wl^T + bl (fp32 out)
__global__ __launch_bounds__(512, 2)
void k_gemm_agg(const float* __restrict__ hbar, const short* __restrict__ Wlt,
                const float* __restrict__ bl, float* __restrict__ out) {
  __shared__ short As[Bb_M][Bb_K];
  __shared__ short Bs[2][Bb_N][Bb_K];
  int t = threadIdx.x;
  int lane = t & 63;
  int w = t >> 6;
  int wm = w >> 2, wn = w & 3;
  int n0 = blockIdx.x * Bb_N;   // 3 blocks, m0 = 0

  GemmAcc g = {};
  gemm_body(&As[0][0], &Bs[0][0][0], hbar, Wlt, 0, n0, HH, g, t);

#pragma unroll
  for (int mi = 0; mi < 4; ++mi) {
    int row = wm * 64 + mi * 16 + ((lane >> 4) * 4);
#pragma unroll
    for (int ni = 0; ni < 4; ++ni) {
      int col = n0 + wn * 64 + ni * 16 + (lane & 15);
      float bv = bl[col];
#pragma unroll
      for (int j = 0; j < 4; ++j)
        out[O_AGGL + (size_t)(row + j) * DD + col] = g.acc[mi][ni][j] + bv;
    }
  }
}

// ---------------------------------------------------------------- scores = agg . pt / temp (masked)
__global__ void k_scores(const short* __restrict__ pt, const float* __restrict__ outbuf,
                         const int* __restrict__ lmask, const int* __restrict__ amask,
                         const float* __restrict__ temp_p, float* __restrict__ scores) {
  int chunk = blockIdx.x;
  int b = blockIdx.y;
  int t = threadIdx.x;
  int w = t >> 6, lane = t & 63;
  __shared__ float agg[MM][HH];
  const float* asrc = outbuf + O_AGGL + (size_t)b * MM * DD;
  for (int i = t; i < MM * HH / 4; i += 256)
    *(float4*)&agg[0][i * 4] = *(const float4*)&asrc[i * 4];
  __syncthreads();
  float inv_temp = 1.0f / fmaxf(fabsf(temp_p[0]), 0.1f);
  for (int i = 0; i < 32; ++i) {
    int l = chunk * 128 + w * 32 + i;
    int is_text = (lmask[b * LL + l] == 0) && (amask[b * LL + l] == 1);
    float acc8[8] = {};
    if (is_text) {
      const short* prow = pt + (size_t)(b * LL + l) * DD;
#pragma unroll
      for (int c = 0; c < 3; ++c) {
        s16x4 pv = *(const s16x4*)&prow[c * 256 + lane * 4];
        float p0 = bf2f(pv[0]), p1 = bf2f(pv[1]), p2 = bf2f(pv[2]), p3 = bf2f(pv[3]);
#pragma unroll
        for (int m = 0; m < 8; ++m) {
          float4 av = *(const float4*)&agg[m][c * 256 + lane * 4];
          acc8[m] += p0 * av.x + p1 * av.y + p2 * av.z + p3 * av.w;
        }
      }
#pragma unroll
      for (int m = 0; m < 8; ++m) {
        float v = acc8[m];
        for (int s = 32; s; s >>= 1) v += __shfl_xor(v, s, 64);
        acc8[m] = v;
      }
    }
    if (lane == 0) {
#pragma unroll
      for (int m = 0; m < 8; ++m)
        scores[(size_t)(b * MM + m) * LL + l] = is_text ? acc8[m] * inv_temp : -1e30f;
    }
  }
}

// ---------------------------------------------------------------- row softmax (in place)
__global__ void k_softmax(float* __restrict__ scores) {
  int row = blockIdx.x;
  float* s = scores + (size_t)row * LL;
  int t = threadIdx.x;
  int w = t >> 6, lane = t & 63;
  float v[8];
  float mx = -1e30f;
#pragma unroll
  for (int i = 0; i < 8; ++i) { v[i] = s[t + 256 * i]; mx = fmaxf(mx, v[i]); }
  for (int sh = 32; sh; sh >>= 1) mx = fmaxf(mx, __shfl_xor(mx, sh, 64));
  __shared__ float wred[4];
  __shared__ float wsum[4];
  if (lane == 0) wred[w] = mx;
  __syncthreads();
  mx = fmaxf(fmaxf(wred[0], wred[1]), fmaxf(wred[2], wred[3]));
  float sum = 0.f;
#pragma unroll
  for (int i = 0; i < 8; ++i) { v[i] = __expf(v[i] - mx); sum += v[i]; }
  for (int sh = 32; sh; sh >>= 1) sum += __shfl_xor(sum, sh, 64);
  if (lane == 0) wsum[w] = sum;
  __syncthreads();
  sum = wsum[0] + wsum[1] + wsum[2] + wsum[3];
  float inv = 1.0f / sum;
#pragma unroll
  for (int i = 0; i < 8; ++i) s[t + 256 * i] = v[i] * inv;
}

// ---------------------------------------------------------------- aggregated_text partials
__global__ void k_aggtext_part(const short* __restrict__ pt, const float* __restrict__ attn,
                               float* __restrict__ part) {
  int lc = blockIdx.x;
  int dt = blockIdx.y;
  int b  = blockIdx.z;
  int t = threadIdx.x;
  int m  = t >> 5;
  int c4 = t & 31;
  __shared__ float at_l[MM][256];
  for (int i = t; i < MM * 256; i += 256) {
    int mm = i >> 8, ll = i & 255;
    at_l[mm][ll] = attn[(size_t)(b * MM + mm) * LL + lc * 256 + ll];
  }
  __syncthreads();
  float ax = 0.f, ay = 0.f, az = 0.f, aw = 0.f;
  const short* p = pt + (size_t)(b * LL + lc * 256) * DD + dt * 128 + c4 * 4;
#pragma unroll 4
  for (int ll = 0; ll < 256; ++ll) {
    s16x4 pv = *(const s16x4*)(p + (size_t)ll * DD);
    float a = at_l[m][ll];
    ax += a * bf2f(pv[0]); ay += a * bf2f(pv[1]);
    az += a * bf2f(pv[2]); aw += a * bf2f(pv[3]);
  }
  float* dst = part + ((size_t)(lc * BB + b) * MM + m) * DD + dt * 128 + c4 * 4;
  float4 acc = {ax, ay, az, aw};
  *(float4*)dst = acc;
}

// ---------------------------------------------------------------- reduce partials + cosine head
__global__ void k_head(const float* __restrict__ part, const float* __restrict__ lscale_p,
                       float* __restrict__ out) {
  int row = blockIdx.x;
  int lane = threadIdx.x;
  int b = row >> 3, m = row & 7;
  const float* al = out + O_AGGL + (size_t)row * DD;
  float* at_out = out + O_AGGT + (size_t)row * DD;
  float dot = 0.f, nt = 0.f, nl = 0.f;
  for (int i = lane; i < DD; i += 64) {
    float a = 0.f;
#pragma unroll
    for (int lc = 0; lc < 8; ++lc)
      a += part[((size_t)(lc * BB + b) * MM + m) * DD + i];
    float c = al[i];
    at_out[i] = a;
    dot += a * c; nt += a * a; nl += c * c;
  }
  for (int s = 32; s; s >>= 1) {
    dot += __shfl_xor(dot, s, 64);
    nt  += __shfl_xor(nt, s, 64);
    nl  += __shfl_xor(nl, s, 64);
  }
  if (lane == 0) {
    float scale = expf(lscale_p[0]);
    float denom = fmaxf(sqrtf(nt), 1e-8f) * fmaxf(sqrtf(nl), 1e-8f);
    out[O_LOGITS + row] = dot / denom * scale;
    out[O_BID + row] = (float)(row >> 3);
    out[O_LID + row] = (float)((row & 7) + 1);
    if (row == 0) out[O_SCALE] = scale;
  }
}

extern "C" void kernel_launch(void* const* d_in, const int* in_sizes, int n_in,
                              void* d_out, int out_size, void* d_ws, size_t ws_size,
                              hipStream_t stream) {
  const float* hs    = (const float*)d_in[0];
  const float* Wt    = (const float*)d_in[1];
  const float* bt    = (const float*)d_in[2];
  const float* Wl    = (const float*)d_in[3];
  const float* bl    = (const float*)d_in[4];
  const float* atemp = (const float*)d_in[5];
  const float* lsc   = (const float*)d_in[6];
  const int*   lmask = (const int*)d_in[7];
  const int*   amask = (const int*)d_in[9];
  float* out = (float*)d_out;
  char* ws = (char*)d_ws;
  short* Wtt    = (short*)(ws + WTT_OFF);
  short* pt     = (short*)(ws + PT_OFF);
  float* scores = (float*)(ws + SC_OFF);
  float* part   = (float*)(ws + PART_OFF);
  short* Wlt    = (short*)(ws + WLT_OFF);
  float* hbar   = (float*)(ws + HBAR_OFF);

  k_wt_transpose<<<dim3(12, 12, 2), 256, 0, stream>>>(Wt, Wl, Wtt, Wlt);
  k_hbar<<<128, 256, 0, stream>>>(hs, lmask, hbar);
  k_gemm_agg<<<3, 512, 0, stream>>>(hbar, Wlt, bl, out);
  k_gemm_pt<<<768, 512, 0, stream>>>(hs, Wtt, bt, pt);
  k_scores<<<dim3(16, 16), 256, 0, stream>>>(pt, out, lmask, amask, atemp, scores);
  k_softmax<<<128, 256, 0, stream>>>(scores);
  k_aggtext_part<<<dim3(8, 6, 16), 256, 0, stream>>>(pt, scores, part);
  k_head<<<128, 64, 0, stream>>>(part, lsc, out);
}

// Round 9
// 137.139 us; speedup vs baseline: 1.6782x; 1.6782x over previous
//
#include <hip/hip_runtime.h>
#include <hip/hip_bf16.h>

typedef __attribute__((ext_vector_type(8))) short s16x8;
typedef __attribute__((ext_vector_type(4))) short s16x4;
typedef __attribute__((ext_vector_type(2))) short s16x2;
typedef __attribute__((ext_vector_type(4))) float f32x4;

#define BB 16
#define LL 2048
#define HH 768
#define DD 768
#define MM 8

// d_out layout (float elements)
#define O_LOGITS 0
#define O_BID    128
#define O_LID    256
#define O_AGGL   384
#define O_SCALE  98688
#define O_AGGT   98689

// ws layout (bytes)
#define WTT_OFF  0u            // 768*768 bf16 = 1179648
#define PT_OFF   1179648u      // 32768*768 bf16 = 50331648
#define SC_OFF   51511296u     // 16*8*2048 fp32 = 1048576
#define PART_OFF 52559872u     // 8*128*768 fp32 = 3145728
#define WLT_OFF  55705600u     // 768*768 bf16 = 1179648
#define HBAR_OFF 56885248u     // 128*768 fp32 = 393216

__device__ __forceinline__ short f2bf(float x) {
  union { float f; unsigned u; } v; v.f = x;
  unsigned r = v.u + 0x7FFFu + ((v.u >> 16) & 1u);
  return (short)(r >> 16);
}
__device__ __forceinline__ float bf2f(short x) {
  union { unsigned u; float f; } v; v.u = ((unsigned)(unsigned short)x) << 16;
  return v.f;
}

// async global->LDS, 16B per lane; LDS dest is wave-uniform base (HW adds lane*16)
#define GLOAD_LDS16(gp, lp) __builtin_amdgcn_global_load_lds( \
    (const __attribute__((address_space(1))) unsigned int*)(gp), \
    (__attribute__((address_space(3))) unsigned int*)(lp), 16, 0, 0)

// ---------------------------------------------------------------- W -> W^T bf16 (Wt and Wl)
__global__ void k_wt_transpose(const float* __restrict__ Wt, const float* __restrict__ Wl,
                               short* __restrict__ Wtt, short* __restrict__ Wlt) {
  __shared__ float tile[64][65];
  const float* src = blockIdx.z ? Wl : Wt;
  short* dst = blockIdx.z ? Wlt : Wtt;
  int kb = blockIdx.x * 64;
  int nb = blockIdx.y * 64;
  int t = threadIdx.x;
  int c = t & 63;
  int r0 = (t >> 6) * 16;
#pragma unroll
  for (int i = 0; i < 16; ++i)
    tile[r0 + i][c] = src[(size_t)(kb + r0 + i) * DD + nb + c];
  __syncthreads();
#pragma unroll
  for (int i = 0; i < 16; ++i)
    dst[(size_t)(nb + r0 + i) * HH + kb + c] = f2bf(tile[c][r0 + i]);
}

// ---------------------------------------------------------------- hbar = segment-mean of hs
__global__ void k_hbar(const float* __restrict__ hs, const int* __restrict__ lmask,
                       float* __restrict__ hbar) {
  int b = blockIdx.x >> 3, m = blockIdx.x & 7;
  int t = threadIdx.x;
  int lane = t & 63, w = t >> 6;
  __shared__ int list[LL];
  __shared__ int nlist_s;
  if (w == 0) {  // deterministic compaction of matching token indices
    int base = 0;
    for (int win = 0; win < LL / 64; ++win) {
      int l = win * 64 + lane;
      bool match = (lmask[b * LL + l] == m + 1);
      unsigned long long mk = __ballot(match);
      if (match) {
        int pos = base + (int)__popcll(mk & ((1ull << lane) - 1ull));
        list[pos] = l;
      }
      base += (int)__popcll(mk);
    }
    if (lane == 0) nlist_s = base;
  }
  __syncthreads();
  int n = nlist_s;
  float inv = 1.0f / (float)(n > 1 ? n : 1);
  float a0 = 0.f, a1 = 0.f, a2 = 0.f;
  for (int i = 0; i < n; ++i) {
    const float* r = hs + (size_t)(b * LL + list[i]) * HH;
    a0 += r[t]; a1 += r[t + 256]; a2 += r[t + 512];
  }
  float* dst = hbar + (size_t)(b * MM + m) * HH;
  dst[t] = a0 * inv; dst[t + 256] = a1 * inv; dst[t + 512] = a2 * inv;
}

// ---------------------------------------------------------------- shared GEMM body
// Round-6 proven config: BM=BN=128, 256 threads. A fp32 reg-staged -> cvt_pk ->
// bf16 LDS (single buffer); B bf16 double-buffered via global_load_lds.
// Full-drain __syncthreads; 16B-chunk XOR swizzle phys = c ^ (row&7) on both
// tiles (0 bank conflicts measured). 3 blocks/CU — protect this: dropping to
// 1-2 blocks/CU serializes the barrier drain (round-8 regression).
#define Bb_M 128
#define Bb_N 128
#define Bb_K 64
#define NTK 12

struct GemmAcc { f32x4 acc[4][4]; };

__device__ __forceinline__ void gemm_body(
    short* AsB, short* BsB,
    const float* A, const short* Bt, int m0, int n0, int lda_k,
    GemmAcc& g, int t) {
  int lane = t & 63;
  int w = t >> 6;
  int wm = w >> 1, wn = w & 1;

  float4 areg[8];

  auto issueA = [&](int kt) {
    const float* Ag = A + (size_t)m0 * lda_k + kt * Bb_K;
#pragma unroll
    for (int i = 0; i < 8; ++i) {
      int slot = i * 256 + t;
      int row = slot >> 4, c = slot & 15;      // 16B fp32 chunk (4 floats)
      areg[i] = *(const float4*)(Ag + (size_t)row * lda_k + c * 4);
    }
  };
  auto issueB = [&](int kt, int buf) {
    const short* Bg = Bt + (size_t)n0 * lda_k + kt * Bb_K;
#pragma unroll
    for (int i = 0; i < 4; ++i) {
      int slot = i * 256 + w * 64 + lane;
      int row = slot >> 3, c = slot & 7;       // 16B bf16 chunk
      int cs = c ^ (row & 7);                  // inverse-swizzled global source
      GLOAD_LDS16(Bg + (size_t)row * lda_k + cs * 8,
                  (char*)BsB + (size_t)buf * 16384 + (size_t)(i * 256 + w * 64) * 16);
    }
  };
  auto writeA = [&]() {   // cvt_pk + swizzled ds_write
#pragma unroll
    for (int i = 0; i < 8; ++i) {
      int slot = i * 256 + t;
      int row = slot >> 4, c = slot & 15;      // c = 8B-unit index of bf16 row
      unsigned d0, d1;
      asm("v_cvt_pk_bf16_f32 %0, %1, %2" : "=v"(d0) : "v"(areg[i].x), "v"(areg[i].y));
      asm("v_cvt_pk_bf16_f32 %0, %1, %2" : "=v"(d1) : "v"(areg[i].z), "v"(areg[i].w));
      int phys = (c >> 1) ^ (row & 7);
      uint2 val = {d0, d1};
      *(uint2*)((char*)AsB + (size_t)row * 128 + phys * 16 + (c & 1) * 8) = val;
    }
  };
  auto compute = [&](int buf) {
#pragma unroll
    for (int kk = 0; kk < 2; ++kk) {
      s16x8 a[4], bb[4];
#pragma unroll
      for (int i = 0; i < 4; ++i) {
        int row = wm * 64 + i * 16 + (lane & 15);
        int p = (kk * 4 + (lane >> 4)) ^ (row & 7);
        a[i] = *(const s16x8*)((const char*)AsB + (size_t)row * 128 + p * 16);
      }
#pragma unroll
      for (int i = 0; i < 4; ++i) {
        int row = wn * 64 + i * 16 + (lane & 15);
        int p = (kk * 4 + (lane >> 4)) ^ (row & 7);
        bb[i] = *(const s16x8*)((const char*)BsB + (size_t)buf * 16384 + (size_t)row * 128 + p * 16);
      }
#pragma unroll
      for (int mi = 0; mi < 4; ++mi)
#pragma unroll
        for (int ni = 0; ni < 4; ++ni)
          g.acc[mi][ni] = __builtin_amdgcn_mfma_f32_16x16x32_bf16(a[mi], bb[ni], g.acc[mi][ni], 0, 0, 0);
    }
  };

  // prologue
  issueA(0); issueB(0, 0);
  writeA();                 // compiler auto-waits the areg loads
  __syncthreads();          // drains B(0) DMA + commits As(0)
  for (int kt = 0; kt < NTK; ++kt) {
    if (kt + 1 < NTK) { issueA(kt + 1); issueB(kt + 1, (kt + 1) & 1); }
    compute(kt & 1);        // kt+1 loads in flight during compute
    __syncthreads();        // drain (one compute-phase after issue); As free
    if (kt + 1 < NTK) {
      writeA();             // As(kt+1)
      __syncthreads();      // As(kt+1) + Bs[nxt] visible
    }
  }
}

// ---------------------------------------------------------------- proj_text GEMM (bf16 out)
__global__ __launch_bounds__(256, 3)
void k_gemm_pt(const float* __restrict__ A, const short* __restrict__ Bt,
               const float* __restrict__ bias, short* __restrict__ C) {
  __shared__ short As[Bb_M][Bb_K];        // 16 KB
  __shared__ short Bs[2][Bb_N][Bb_K];     // 32 KB
  int t = threadIdx.x;
  int lane = t & 63;
  int w = t >> 6;
  int wm = w >> 1, wn = w & 1;
  // XCD-affinity remap: 6 N-tiles of one M-panel land on the same XCD
  int id = blockIdx.x;           // 1536
  int xcd = id & 7, q = id >> 3; // q 0..191
  int m0 = ((q / 6) * 8 + xcd) * Bb_M;
  int n0 = (q % 6) * Bb_N;

  GemmAcc g = {};
  gemm_body(&As[0][0], &Bs[0][0][0], A, Bt, m0, n0, HH, g, t);

#pragma unroll
  for (int mi = 0; mi < 4; ++mi) {
    int row = m0 + wm * 64 + mi * 16 + ((lane >> 4) * 4);
#pragma unroll
    for (int ni = 0; ni < 4; ++ni) {
      int col = n0 + wn * 64 + ni * 16 + (lane & 15);
      float bv = bias[col];
#pragma unroll
      for (int j = 0; j < 4; ++j)
        C[(size_t)(row + j) * DD + col] = f2bf(g.acc[mi][ni][j] + bv);
    }
  }
}

// ---------------------------------------------------------------- agg = hbar @ Wl^T + bl (fp32 out)
__global__ __launch_bounds__(256, 3)
void k_gemm_agg(const float* __restrict__ hbar, const short* __restrict__ Wlt,
                const float* __restrict__ bl, float* __restrict__ out) {
  __shared__ short As[Bb_M][Bb_K];
  __shared__ short Bs[2][Bb_N][Bb_K];
  int t = threadIdx.x;
  int lane = t & 63;
  int w = t >> 6;
  int wm = w >> 1, wn = w & 1;
  int n0 = blockIdx.x * Bb_N;   // 6 blocks, m0 = 0

  GemmAcc g = {};
  gemm_body(&As[0][0], &Bs[0][0][0], hbar, Wlt, 0, n0, HH, g, t);

#pragma unroll
  for (int mi = 0; mi < 4; ++mi) {
    int row = wm * 64 + mi * 16 + ((lane >> 4) * 4);
#pragma unroll
    for (int ni = 0; ni < 4; ++ni) {
      int col = n0 + wn * 64 + ni * 16 + (lane & 15);
      float bv = bl[col];
#pragma unroll
      for (int j = 0; j < 4; ++j)
        out[O_AGGL + (size_t)(row + j) * DD + col] = g.acc[mi][ni][j] + bv;
    }
  }
}

// ---------------------------------------------------------------- scores via MFMA
// S[tok][m] = pt[tok][:] . agg[m][:]; 64-token tile per block, agg staged once
// as bf16 in padded LDS, pt tile double-buffered via swizzled global_load_lds.
#define SCHUNK 64
__global__ __launch_bounds__(256, 3)
void k_scores_mfma(const short* __restrict__ pt, const float* __restrict__ outbuf,
                   const int* __restrict__ lmask, const int* __restrict__ amask,
                   const float* __restrict__ temp_p, float* __restrict__ scores) {
  __shared__ short As[2][SCHUNK][64];   // pt tile (swizzled 16B chunks), 16 KB
  __shared__ short Bs[16][776];         // agg bf16, +8 pad -> 2-way banks (free)
  int chunk = blockIdx.x;               // 32 chunks of 64 tokens
  int b = blockIdx.y;                   // 16
  int t = threadIdx.x;
  int lane = t & 63, w = t >> 6;

  // stage agg (8 real rows) as bf16; zero rows 8..15
  const float* asrc = outbuf + O_AGGL + (size_t)b * MM * DD;
  for (int c = t; c < DD; c += 256) {
#pragma unroll
    for (int r = 0; r < 8; ++r) Bs[r][c] = f2bf(asrc[(size_t)r * DD + c]);
#pragma unroll
    for (int r = 8; r < 16; ++r) Bs[r][c] = 0;
  }

  const short* Pg = pt + (size_t)(b * LL + chunk * SCHUNK) * DD;
  auto stage = [&](int kt, int buf) {
#pragma unroll
    for (int i = 0; i < 2; ++i) {
      int slot = i * 256 + t;
      int row = slot >> 3, c = slot & 7;
      int cs = c ^ (row & 7);
      GLOAD_LDS16(Pg + (size_t)row * DD + kt * 64 + cs * 8,
                  (char*)&As[0][0][0] + (size_t)buf * 8192 + (size_t)(i * 256 + w * 64) * 16);
    }
  };

  f32x4 acc = {};
  stage(0, 0);
  __syncthreads();            // agg staged + As(0) drained
  for (int kt = 0; kt < 12; ++kt) {
    if (kt + 1 < 12) stage(kt + 1, (kt + 1) & 1);
#pragma unroll
    for (int kk = 0; kk < 2; ++kk) {
      int arow = w * 16 + (lane & 15);
      int p = (kk * 4 + (lane >> 4)) ^ (arow & 7);
      s16x8 a = *(const s16x8*)((const char*)&As[0][0][0] +
                                (size_t)(kt & 1) * 8192 + (size_t)arow * 128 + p * 16);
      s16x8 bfr = *(const s16x8*)&Bs[lane & 15][kt * 64 + kk * 32 + (lane >> 4) * 8];
      acc = __builtin_amdgcn_mfma_f32_16x16x32_bf16(a, bfr, acc, 0, 0, 0);
    }
    __syncthreads();          // drains As(kt+1) DMA; all waves done with As(kt)
  }

  float inv_temp = 1.0f / fmaxf(fabsf(temp_p[0]), 0.1f);
  int m = lane & 15;
  int tok0 = chunk * SCHUNK + w * 16 + (lane >> 4) * 4;
  if (m < MM) {
    int4 lm = *(const int4*)&lmask[b * LL + tok0];
    int4 am = *(const int4*)&amask[b * LL + tok0];
    float4 o;
    o.x = (lm.x == 0 && am.x == 1) ? acc[0] * inv_temp : -1e30f;
    o.y = (lm.y == 0 && am.y == 1) ? acc[1] * inv_temp : -1e30f;
    o.z = (lm.z == 0 && am.z == 1) ? acc[2] * inv_temp : -1e30f;
    o.w = (lm.w == 0 && am.w == 1) ? acc[3] * inv_temp : -1e30f;
    *(float4*)&scores[(size_t)(b * MM + m) * LL + tok0] = o;
  }
}

// ---------------------------------------------------------------- row softmax (in place)
__global__ void k_softmax(float* __restrict__ scores) {
  int row = blockIdx.x;
  float* s = scores + (size_t)row * LL;
  int t = threadIdx.x;
  int w = t >> 6, lane = t & 63;
  float v[8];
  float mx = -1e30f;
#pragma unroll
  for (int i = 0; i < 8; ++i) { v[i] = s[t + 256 * i]; mx = fmaxf(mx, v[i]); }
  for (int sh = 32; sh; sh >>= 1) mx = fmaxf(mx, __shfl_xor(mx, sh, 64));
  __shared__ float wred[4];
  __shared__ float wsum[4];
  if (lane == 0) wred[w] = mx;
  __syncthreads();
  mx = fmaxf(fmaxf(wred[0], wred[1]), fmaxf(wred[2], wred[3]));
  float sum = 0.f;
#pragma unroll
  for (int i = 0; i < 8; ++i) { v[i] = __expf(v[i] - mx); sum += v[i]; }
  for (int sh = 32; sh; sh >>= 1) sum += __shfl_xor(sum, sh, 64);
  if (lane == 0) wsum[w] = sum;
  __syncthreads();
  sum = wsum[0] + wsum[1] + wsum[2] + wsum[3];
  float inv = 1.0f / sum;
#pragma unroll
  for (int i = 0; i < 8; ++i) s[t + 256 * i] = v[i] * inv;
}

// ---------------------------------------------------------------- aggregated_text partials
__global__ void k_aggtext_part(const short* __restrict__ pt, const float* __restrict__ attn,
                               float* __restrict__ part) {
  int lc = blockIdx.x;
  int dt = blockIdx.y;
  int b  = blockIdx.z;
  int t = threadIdx.x;
  int m  = t >> 5;
  int c4 = t & 31;
  __shared__ float at_l[MM][256];
  for (int i = t; i < MM * 256; i += 256) {
    int mm = i >> 8, ll = i & 255;
    at_l[mm][ll] = attn[(size_t)(b * MM + mm) * LL + lc * 256 + ll];
  }
  __syncthreads();
  float ax = 0.f, ay = 0.f, az = 0.f, aw = 0.f;
  const short* p = pt + (size_t)(b * LL + lc * 256) * DD + dt * 128 + c4 * 4;
#pragma unroll 4
  for (int ll = 0; ll < 256; ++ll) {
    s16x4 pv = *(const s16x4*)(p + (size_t)ll * DD);
    float a = at_l[m][ll];
    ax += a * bf2f(pv[0]); ay += a * bf2f(pv[1]);
    az += a * bf2f(pv[2]); aw += a * bf2f(pv[3]);
  }
  float* dst = part + ((size_t)(lc * BB + b) * MM + m) * DD + dt * 128 + c4 * 4;
  float4 acc = {ax, ay, az, aw};
  *(float4*)dst = acc;
}

// ---------------------------------------------------------------- reduce partials + cosine head
__global__ void k_head(const float* __restrict__ part, const float* __restrict__ lscale_p,
                       float* __restrict__ out) {
  int row = blockIdx.x;
  int lane = threadIdx.x;
  int b = row >> 3, m = row & 7;
  const float* al = out + O_AGGL + (size_t)row * DD;
  float* at_out = out + O_AGGT + (size_t)row * DD;
  float dot = 0.f, nt = 0.f, nl = 0.f;
  for (int i = lane; i < DD; i += 64) {
    float a = 0.f;
#pragma unroll
    for (int lc = 0; lc < 8; ++lc)
      a += part[((size_t)(lc * BB + b) * MM + m) * DD + i];
    float c = al[i];
    at_out[i] = a;
    dot += a * c; nt += a * a; nl += c * c;
  }
  for (int s = 32; s; s >>= 1) {
    dot += __shfl_xor(dot, s, 64);
    nt  += __shfl_xor(nt, s, 64);
    nl  += __shfl_xor(nl, s, 64);
  }
  if (lane == 0) {
    float scale = expf(lscale_p[0]);
    float denom = fmaxf(sqrtf(nt), 1e-8f) * fmaxf(sqrtf(nl), 1e-8f);
    out[O_LOGITS + row] = dot / denom * scale;
    out[O_BID + row] = (float)(row >> 3);
    out[O_LID + row] = (float)((row & 7) + 1);
    if (row == 0) out[O_SCALE] = scale;
  }
}

extern "C" void kernel_launch(void* const* d_in, const int* in_sizes, int n_in,
                              void* d_out, int out_size, void* d_ws, size_t ws_size,
                              hipStream_t stream) {
  const float* hs    = (const float*)d_in[0];
  const float* Wt    = (const float*)d_in[1];
  const float* bt    = (const float*)d_in[2];
  const float* Wl    = (const float*)d_in[3];
  const float* bl    = (const float*)d_in[4];
  const float* atemp = (const float*)d_in[5];
  const float* lsc   = (const float*)d_in[6];
  const int*   lmask = (const int*)d_in[7];
  const int*   amask = (const int*)d_in[9];
  float* out = (float*)d_out;
  char* ws = (char*)d_ws;
  short* Wtt    = (short*)(ws + WTT_OFF);
  short* pt     = (short*)(ws + PT_OFF);
  float* scores = (float*)(ws + SC_OFF);
  float* part   = (float*)(ws + PART_OFF);
  short* Wlt    = (short*)(ws + WLT_OFF);
  float* hbar   = (float*)(ws + HBAR_OFF);

  k_wt_transpose<<<dim3(12, 12, 2), 256, 0, stream>>>(Wt, Wl, Wtt, Wlt);
  k_hbar<<<128, 256, 0, stream>>>(hs, lmask, hbar);
  k_gemm_agg<<<6, 256, 0, stream>>>(hbar, Wlt, bl, out);
  k_gemm_pt<<<1536, 256, 0, stream>>>(hs, Wtt, bt, pt);
  k_scores_mfma<<<dim3(32, 16), 256, 0, stream>>>(pt, out, lmask, amask, atemp, scores);
  k_softmax<<<128, 256, 0, stream>>>(scores);
  k_aggtext_part<<<dim3(8, 6, 16), 256, 0, stream>>>(pt, scores, part);
  k_head<<<128, 64, 0, stream>>>(part, lsc, out);
}